// Round 2
// baseline (343.635 us; speedup 1.0000x reference)
//
#include <hip/hip_runtime.h>

// Problem: per-batch segment_sum over sorted segment ids.
// B=16, L=4096, H=768, fp32. out[b,j,:] = sum_{p: seg[b,p]==j} x[b,p,:].
// Sorted ids => token j's wordpieces are the contiguous range
// [lower_bound(seg_b, j), lower_bound(seg_b, j+1)).
#define BB 16
#define LL 4096
#define H4 192    // 768 floats = 192 float4 per row
#define SP 4104   // starts row stride (needs LL+1 entries; padded)
#define TT 8      // tokens per wave (chunk)
#define LOG2T 3

// ---------------------------------------------------------------------------
// Kernel A: precompute starts[b][j] = lower_bound(seg_b, j) for j in [0, LL].
// Thread handles one wordpiece position p. Positions partition [0, LL] into
// runs (seg[p-1], seg[p]] -> lb = p (with seg[-1] := -1), plus the tail
// (seg[LL-1], LL] -> lb = LL. Every entry written every call (poison-safe).
// ---------------------------------------------------------------------------
__global__ __launch_bounds__(256) void bounds_kernel(
    const int* __restrict__ seg, int* __restrict__ starts) {
    int b = blockIdx.x >> 4;                       // 16 blocks per batch row
    int p = ((blockIdx.x & 15) << 8) | threadIdx.x;
    const int* __restrict__ sb = seg + (b << 12);
    int* __restrict__ st = starts + b * SP;

    int cur  = sb[p];
    int prev = (p == 0) ? -1 : sb[p - 1];
    for (int j = prev + 1; j <= cur; ++j) st[j] = p;
    if (p == LL - 1)
        for (int j = cur + 1; j <= LL; ++j) st[j] = LL;
}

// ---------------------------------------------------------------------------
// Kernel B: one wave per TT-token chunk. The chunk owns the contiguous
// wordpiece range [starts[j0], starts[j0+TT]) -- token-aligned, so no
// cross-wave sharing and no atomics. The wave streams those rows with a
// depth-2 software pipeline (load row p+1 + seg[p+1] while accumulating
// row p), flushing each completed token row and zero-filling gap tokens.
// Every out row in the chunk is written exactly once (poison-safe).
// Grid: B*L/TT = 8192 waves = 2048 blocks (vs 16384 before -- the round-1
// profile showed a latency/dispatch-bound kernel: 31% HBM, 4% VALU, 57% occ).
// ---------------------------------------------------------------------------
__global__ __launch_bounds__(256) void segsum_stream_kernel(
    const float4* __restrict__ x, const int* __restrict__ seg,
    const int* __restrict__ starts, float4* __restrict__ out) {
    int gtid = blockIdx.x * blockDim.x + threadIdx.x;
    int wave = gtid >> 6;                 // 0 .. B*L/TT-1
    int lane = gtid & 63;
    int b    = wave >> (12 - LOG2T);      // / (L/TT)
    int j0   = (wave & ((LL >> LOG2T) - 1)) << LOG2T;

    const int* __restrict__ st = starts + b * SP;
    int s = st[j0];
    int e = st[j0 + TT];

    const float4* __restrict__ xb = x + (size_t)b * (LL * H4);
    const int*    __restrict__ sb = seg + (b << 12);
    float4*       __restrict__ ob = out + ((size_t)(b << 12) + j0) * H4 + lane;

    const float4 z = make_float4(0.f, 0.f, 0.f, 0.f);
    float4 a0 = z, a1 = z, a2 = z;
    int cur = j0;                         // token currently accumulating

    // pipeline prime: row s
    float4 n0 = z, n1 = z, n2 = z;
    int tn = 0;
    if (s < e) {
        const float4* r = xb + (size_t)s * H4 + lane;
        n0 = r[0]; n1 = r[64]; n2 = r[128];
        tn = sb[s];
    }

    for (int p = s; p < e; ++p) {
        float4 c0 = n0, c1 = n1, c2 = n2;
        int t = tn;
        // prefetch row p+1 (clamped; redundant cache-hit on last iter)
        int pn = (p + 1 < e) ? (p + 1) : p;
        const float4* r = xb + (size_t)pn * H4 + lane;
        n0 = r[0]; n1 = r[64]; n2 = r[128];
        tn = sb[pn];

        if (t != cur) {                   // wave-uniform branch
            float4* orow = ob + (size_t)(cur - j0) * H4;
            orow[0] = a0; orow[64] = a1; orow[128] = a2;
            for (int g = cur + 1; g < t; ++g) {   // empty tokens -> zeros
                float4* og = ob + (size_t)(g - j0) * H4;
                og[0] = z; og[64] = z; og[128] = z;
            }
            a0 = z; a1 = z; a2 = z;
            cur = t;
        }
        a0.x += c0.x; a0.y += c0.y; a0.z += c0.z; a0.w += c0.w;
        a1.x += c1.x; a1.y += c1.y; a1.z += c1.z; a1.w += c1.w;
        a2.x += c2.x; a2.y += c2.y; a2.z += c2.z; a2.w += c2.w;
    }

    // final flush: current token, then zeros up to chunk end.
    // (if s==e the whole chunk is empty: writes zeros for all TT tokens.)
    float4* orow = ob + (size_t)(cur - j0) * H4;
    orow[0] = a0; orow[64] = a1; orow[128] = a2;
    for (int g = cur + 1; g < j0 + TT; ++g) {
        float4* og = ob + (size_t)(g - j0) * H4;
        og[0] = z; og[64] = z; og[128] = z;
    }
}

// ---------------------------------------------------------------------------
// Fallback: fused kernel (in-wave 64-ary ballot search) if ws unavailable.
// ---------------------------------------------------------------------------
__global__ __launch_bounds__(256) void segsum_fused_kernel(
    const float4* __restrict__ x, const int* __restrict__ seg,
    float4* __restrict__ out) {
    int gtid = blockIdx.x * blockDim.x + threadIdx.x;
    int wave = gtid >> 6;
    int lane = gtid & 63;
    int b = wave >> 12;
    int j = wave & (LL - 1);

    const int* __restrict__ sb = seg + ((size_t)b << 12);

    int v1 = sb[lane << 6];
    unsigned long long ms = __ballot(v1 >= j);
    unsigned long long me = __ballot(v1 > j);

    int s, e;
    if (ms & 1ull) {
        s = 0;
    } else {
        int f = ms ? (__ffsll((unsigned long long)ms) - 1) : 64;
        int base = ((f - 1) << 6) + 1;
        int p2 = base + lane;
        int v2 = (p2 < LL) ? sb[p2] : 0x7fffffff;
        unsigned long long m2 = __ballot(v2 >= j);
        s = base + __ffsll(m2) - 1;
    }
    if (me & 1ull) {
        e = 0;
    } else {
        int f = me ? (__ffsll((unsigned long long)me) - 1) : 64;
        int base = ((f - 1) << 6) + 1;
        int p2 = base + lane;
        int v2 = (p2 < LL) ? sb[p2] : 0x7fffffff;
        unsigned long long m2 = __ballot(v2 > j);
        e = base + __ffsll(m2) - 1;
    }

    float4 a0 = make_float4(0.f, 0.f, 0.f, 0.f);
    float4 a1 = a0, a2 = a0;

    const float4* xb = x + (size_t)b * LL * H4;
    for (int p = s; p < e; ++p) {
        const float4* row = xb + (size_t)p * H4 + lane;
        float4 v0 = row[0];
        float4 vA = row[64];
        float4 vB = row[128];
        a0.x += v0.x; a0.y += v0.y; a0.z += v0.z; a0.w += v0.w;
        a1.x += vA.x; a1.y += vA.y; a1.z += vA.z; a1.w += vA.w;
        a2.x += vB.x; a2.y += vB.y; a2.z += vB.z; a2.w += vB.w;
    }

    float4* orow = out + (size_t)wave * H4 + lane;
    orow[0]   = a0;
    orow[64]  = a1;
    orow[128] = a2;
}

extern "C" void kernel_launch(void* const* d_in, const int* in_sizes, int n_in,
                              void* d_out, int out_size, void* d_ws, size_t ws_size,
                              hipStream_t stream) {
    const float* x   = (const float*)d_in[0];   // (B, L, H) fp32
    const int*   seg = (const int*)d_in[1];     // (B, L) int32, sorted per row
    float* out = (float*)d_out;                 // (B, L, H) fp32

    size_t need = (size_t)BB * SP * sizeof(int);   // 262 KB bound table
    if (d_ws != nullptr && ws_size >= need) {
        int* starts = (int*)d_ws;
        // Kernel A: 16 blocks per batch row, one thread per wordpiece.
        bounds_kernel<<<BB * 16, 256, 0, stream>>>(seg, starts);
        // Kernel B: B*L/TT waves, 4 waves per 256-thread block.
        segsum_stream_kernel<<<(BB * (LL >> LOG2T)) / 4, 256, 0, stream>>>(
            (const float4*)x, seg, starts, (float4*)out);
    } else {
        segsum_fused_kernel<<<(BB * LL) / 4, 256, 0, stream>>>(
            (const float4*)x, seg, (float4*)out);
    }
}

// Round 3
// 342.898 us; speedup vs baseline: 1.0022x; 1.0022x over previous
//
#include <hip/hip_runtime.h>

// Problem: per-batch segment_sum over sorted segment ids.
// B=16, L=4096, H=768, fp32. out[b,j,:] = sum_{p: seg[b,p]==j} x[b,p,:].
// Sorted ids => token j's wordpieces are the contiguous range
// [lower_bound(seg_b, j), lower_bound(seg_b, j+1)).
//
// Round-3 structure: ONE kernel. Each wave owns a TT=8-token chunk
// [j0, j0+8). It computes the chunk's wordpiece range [lb(j0), lb(j0+8))
// with the round-0-verified 64-ary ballot search (2 searches amortized over
// 8 tokens, vs 2 per token in round 0), then streams those rows with the
// round-2-verified depth-2 pipelined loop, flushing each token's row once.
// Grid = 2048 blocks = exactly one full resident generation (32 waves/CU).
// Regular stores (NT stores were the round-1 regression suspect).
#define BB 16
#define LL 4096
#define H4 192    // 768 floats = 192 float4 per row
#define TT 8      // tokens per wave
#define LOG2T 3

__global__ __launch_bounds__(256) void segsum_chunk_kernel(
    const float4* __restrict__ x, const int* __restrict__ seg,
    float4* __restrict__ out) {
    int gtid = blockIdx.x * blockDim.x + threadIdx.x;
    int wave = gtid >> 6;                 // 0 .. B*L/TT-1
    int lane = gtid & 63;
    int b    = wave >> (12 - LOG2T);      // / (L/TT)
    int j0   = (wave & ((LL >> LOG2T) - 1)) << LOG2T;
    int j1   = j0 + TT;                   // exclusive token end

    const int* __restrict__ sb = seg + ((size_t)b << 12);

    // ---- chunk bounds: s = lower_bound(j0), e = lower_bound(j1) ----
    // step-1 probe (whole row, stride 64) shared by both bounds
    int v1 = sb[lane << 6];
    unsigned long long ms = __ballot(v1 >= j0);
    unsigned long long me = __ballot(v1 >= j1);

    int s, e;
    if (ms & 1ull) {
        s = 0;                            // seg[0] >= j0
    } else {
        int f = ms ? (__ffsll((unsigned long long)ms) - 1) : 64;
        int base = ((f - 1) << 6) + 1;    // search (f-1)*64+1 .. f*64
        int p2 = base + lane;
        int v2 = (p2 < LL) ? sb[p2] : 0x7fffffff;   // seg[L] := +inf
        unsigned long long m2 = __ballot(v2 >= j0); // lane 63 always eligible
        s = base + __ffsll(m2) - 1;
    }
    if (me & 1ull) {
        e = 0;
    } else {
        int f = me ? (__ffsll((unsigned long long)me) - 1) : 64;
        int base = ((f - 1) << 6) + 1;
        int p2 = base + lane;
        int v2 = (p2 < LL) ? sb[p2] : 0x7fffffff;
        unsigned long long m2 = __ballot(v2 >= j1);
        e = base + __ffsll(m2) - 1;
    }

    // ---- stream rows [s, e), flush per token (round-2-verified loop) ----
    const float4* __restrict__ xb = x + (size_t)b * (LL * H4);
    float4*       __restrict__ ob = out + ((size_t)(b << 12) + j0) * H4 + lane;

    const float4 z = make_float4(0.f, 0.f, 0.f, 0.f);
    float4 a0 = z, a1 = z, a2 = z;
    int cur = j0;                         // token currently accumulating

    // pipeline prime: row s
    float4 n0 = z, n1 = z, n2 = z;
    int tn = 0;
    if (s < e) {
        const float4* r = xb + (size_t)s * H4 + lane;
        n0 = r[0]; n1 = r[64]; n2 = r[128];
        tn = sb[s];
    }

    for (int p = s; p < e; ++p) {
        float4 c0 = n0, c1 = n1, c2 = n2;
        int t = tn;
        // prefetch row p+1 (clamped; redundant cache-hit on last iter)
        int pn = (p + 1 < e) ? (p + 1) : p;
        const float4* r = xb + (size_t)pn * H4 + lane;
        n0 = r[0]; n1 = r[64]; n2 = r[128];
        tn = sb[pn];

        if (t != cur) {                   // wave-uniform branch
            float4* orow = ob + (size_t)(cur - j0) * H4;
            orow[0] = a0; orow[64] = a1; orow[128] = a2;
            for (int g = cur + 1; g < t; ++g) {   // empty tokens -> zeros
                float4* og = ob + (size_t)(g - j0) * H4;
                og[0] = z; og[64] = z; og[128] = z;
            }
            a0 = z; a1 = z; a2 = z;
            cur = t;
        }
        a0.x += c0.x; a0.y += c0.y; a0.z += c0.z; a0.w += c0.w;
        a1.x += c1.x; a1.y += c1.y; a1.z += c1.z; a1.w += c1.w;
        a2.x += c2.x; a2.y += c2.y; a2.z += c2.z; a2.w += c2.w;
    }

    // final flush: current token, then zeros up to chunk end.
    // (if s==e the whole chunk is empty: zeros for all TT tokens.)
    float4* orow = ob + (size_t)(cur - j0) * H4;
    orow[0] = a0; orow[64] = a1; orow[128] = a2;
    for (int g = cur + 1; g < j1; ++g) {
        float4* og = ob + (size_t)(g - j0) * H4;
        og[0] = z; og[64] = z; og[128] = z;
    }
}

extern "C" void kernel_launch(void* const* d_in, const int* in_sizes, int n_in,
                              void* d_out, int out_size, void* d_ws, size_t ws_size,
                              hipStream_t stream) {
    const float* x   = (const float*)d_in[0];   // (B, L, H) fp32
    const int*   seg = (const int*)d_in[1];     // (B, L) int32, sorted per row
    float* out = (float*)d_out;                 // (B, L, H) fp32
    (void)d_ws; (void)ws_size;

    // B*L/TT waves, 4 waves per 256-thread block -> 2048 blocks
    int nblocks = (BB * (LL >> LOG2T)) / 4;
    segsum_chunk_kernel<<<nblocks, 256, 0, stream>>>(
        (const float4*)x, seg, (float4*)out);
}

// Round 4
// 333.197 us; speedup vs baseline: 1.0313x; 1.0291x over previous
//
#include <hip/hip_runtime.h>

// Problem: per-batch segment_sum over sorted segment ids.
// B=16, L=4096, H=768, fp32. out[b,j,:] = sum_{p: seg[b,p]==j} x[b,p,:].
// Sorted ids => token j's wordpieces are the contiguous range
// [lower_bound(seg_b, j), lower_bound(seg_b, j+1)).
//
// Round-4 structure: the round-0 champion (one wave per token, 16384 blocks,
// plain stores -- empirically beat TT=8 chunking by ~14us and NT stores by
// ~10us) with its ONLY remaining overhead removed: the in-wave ballot search
// (64-line stride-64 gather + 2 step-2 gathers per wave, ~75% extra L1/TA
// line traffic vs the useful stream) is replaced by a 2-dword broadcast read
// of a precomputed bounds table, hoisted to SGPRs via readfirstlane.
#define BB 16
#define LL 4096
#define H4 192    // 768 floats = 192 float4 per row
#define SP 4104   // starts row stride (needs LL+1 entries; padded for align)

// ---------------------------------------------------------------------------
// Kernel A (verified rounds 1-2): starts[b][j] = lower_bound(seg_b, j),
// j in [0, LL]. Thread p writes runs (seg[p-1], seg[p]] -> p (seg[-1]:=-1);
// thread L-1 also writes (seg[L-1], LL] -> LL. Every entry written every
// call (poison-safe).
// ---------------------------------------------------------------------------
__global__ __launch_bounds__(256) void bounds_kernel(
    const int* __restrict__ seg, int* __restrict__ starts) {
    int b = blockIdx.x >> 4;                       // 16 blocks per batch row
    int p = ((blockIdx.x & 15) << 8) | threadIdx.x;
    const int* __restrict__ sb = seg + (b << 12);
    int* __restrict__ st = starts + b * SP;

    int cur  = sb[p];
    int prev = (p == 0) ? -1 : sb[p - 1];
    for (int j = prev + 1; j <= cur; ++j) st[j] = p;
    if (p == LL - 1)
        for (int j = cur + 1; j <= LL; ++j) st[j] = LL;
}

// ---------------------------------------------------------------------------
// Kernel B: one wave per output token (b, j) -- round-0 grid and loop body.
// Bounds come from the table: two broadcast dword loads (all 64 lanes same
// address, L2-hit), forced scalar with readfirstlane. Then lane i gather-sums
// float4 columns {i, i+64, i+128} over rows [s, e) and stores the output row
// with plain coalesced stores (zeros for empty tokens -> poison overwritten).
// ---------------------------------------------------------------------------
__global__ __launch_bounds__(256) void segsum_table_kernel(
    const float4* __restrict__ x, const int* __restrict__ starts,
    float4* __restrict__ out) {
    int gtid = blockIdx.x * blockDim.x + threadIdx.x;
    int wave = gtid >> 6;          // 0 .. B*L-1
    int lane = gtid & 63;
    int b = wave >> 12;            // / L
    int j = wave & (LL - 1);       // % L

    const int* __restrict__ st = starts + b * SP + j;
    int s = __builtin_amdgcn_readfirstlane(st[0]);   // lb(j)   -> SGPR
    int e = __builtin_amdgcn_readfirstlane(st[1]);   // lb(j+1) -> SGPR

    float4 a0 = make_float4(0.f, 0.f, 0.f, 0.f);
    float4 a1 = a0, a2 = a0;

    const float4* xb = x + (size_t)b * LL * H4;
    for (int p = s; p < e; ++p) {
        const float4* row = xb + (size_t)p * H4 + lane;
        float4 v0 = row[0];
        float4 vA = row[64];
        float4 vB = row[128];
        a0.x += v0.x; a0.y += v0.y; a0.z += v0.z; a0.w += v0.w;
        a1.x += vA.x; a1.y += vA.y; a1.z += vA.z; a1.w += vA.w;
        a2.x += vB.x; a2.y += vB.y; a2.z += vB.z; a2.w += vB.w;
    }

    float4* orow = out + (size_t)wave * H4 + lane;
    orow[0]   = a0;
    orow[64]  = a1;
    orow[128] = a2;
}

// ---------------------------------------------------------------------------
// Fallback: round-0 champion verbatim (in-wave 64-ary ballot search) in case
// the workspace is unavailable/too small. Known-good at ~84.6 us.
// ---------------------------------------------------------------------------
__global__ __launch_bounds__(256) void segsum_fused_kernel(
    const float4* __restrict__ x, const int* __restrict__ seg,
    float4* __restrict__ out) {
    int gtid = blockIdx.x * blockDim.x + threadIdx.x;
    int wave = gtid >> 6;
    int lane = gtid & 63;
    int b = wave >> 12;
    int j = wave & (LL - 1);

    const int* __restrict__ sb = seg + ((size_t)b << 12);

    int v1 = sb[lane << 6];
    unsigned long long ms = __ballot(v1 >= j);
    unsigned long long me = __ballot(v1 > j);

    int s, e;
    if (ms & 1ull) {
        s = 0;
    } else {
        int f = ms ? (__ffsll((unsigned long long)ms) - 1) : 64;
        int base = ((f - 1) << 6) + 1;
        int p2 = base + lane;
        int v2 = (p2 < LL) ? sb[p2] : 0x7fffffff;
        unsigned long long m2 = __ballot(v2 >= j);
        s = base + __ffsll(m2) - 1;
    }
    if (me & 1ull) {
        e = 0;
    } else {
        int f = me ? (__ffsll((unsigned long long)me) - 1) : 64;
        int base = ((f - 1) << 6) + 1;
        int p2 = base + lane;
        int v2 = (p2 < LL) ? sb[p2] : 0x7fffffff;
        unsigned long long m2 = __ballot(v2 > j);
        e = base + __ffsll(m2) - 1;
    }

    float4 a0 = make_float4(0.f, 0.f, 0.f, 0.f);
    float4 a1 = a0, a2 = a0;

    const float4* xb = x + (size_t)b * LL * H4;
    for (int p = s; p < e; ++p) {
        const float4* row = xb + (size_t)p * H4 + lane;
        float4 v0 = row[0];
        float4 vA = row[64];
        float4 vB = row[128];
        a0.x += v0.x; a0.y += v0.y; a0.z += v0.z; a0.w += v0.w;
        a1.x += vA.x; a1.y += vA.y; a1.z += vA.z; a1.w += vA.w;
        a2.x += vB.x; a2.y += vB.y; a2.z += vB.z; a2.w += vB.w;
    }

    float4* orow = out + (size_t)wave * H4 + lane;
    orow[0]   = a0;
    orow[64]  = a1;
    orow[128] = a2;
}

extern "C" void kernel_launch(void* const* d_in, const int* in_sizes, int n_in,
                              void* d_out, int out_size, void* d_ws, size_t ws_size,
                              hipStream_t stream) {
    const float* x   = (const float*)d_in[0];   // (B, L, H) fp32
    const int*   seg = (const int*)d_in[1];     // (B, L) int32, sorted per row
    float* out = (float*)d_out;                 // (B, L, H) fp32

    size_t need = (size_t)BB * SP * sizeof(int);   // 262 KB bound table
    if (d_ws != nullptr && ws_size >= need) {
        int* starts = (int*)d_ws;
        // Kernel A: 16 blocks per batch row, one thread per wordpiece.
        bounds_kernel<<<BB * 16, 256, 0, stream>>>(seg, starts);
        // Kernel B: round-0 grid -- B*L waves, 4 per 256-thread block.
        segsum_table_kernel<<<(BB * LL) / 4, 256, 0, stream>>>(
            (const float4*)x, starts, (float4*)out);
    } else {
        segsum_fused_kernel<<<(BB * LL) / 4, 256, 0, stream>>>(
            (const float4*)x, seg, (float4*)out);
    }
}